// Round 8
// baseline (349.284 us; speedup 1.0000x reference)
//
#include <hip/hip_runtime.h>

#define B_ROWS 8192
#define IN_F 512
#define OUT_F 1024
#define K_TOT 1536

#define BM 64
#define BN 64
#define BK 32
#define NITER (K_TOT / BK)          // 48

#define A4_COUNT (B_ROWS * (K_TOT / 4))       // 3,145,728 float4 tasks
#define W4_COUNT (OUT_F  * (K_TOT / 4))       //   393,216
#define CAST_BLOCKS ((A4_COUNT + W4_COUNT) / 1024)   // 3456 (4 tasks/thread)
#define GEMM_BLOCKS ((B_ROWS / BM) * (OUT_F / BN))   // 2048

typedef short bfrag __attribute__((ext_vector_type(8)));   // 8 bf16 = 4 VGPRs
typedef float f4    __attribute__((ext_vector_type(4)));

// round-to-nearest-even fp32 -> bf16, packed pairwise into a dword
__device__ __forceinline__ unsigned int pack2bf(float a, float b) {
    unsigned int ua = __float_as_uint(a);
    unsigned int ub = __float_as_uint(b);
    ua = (ua + 0x7fffu + ((ua >> 16) & 1u)) >> 16;
    ub = (ub + 0x7fffu + ((ub >> 16) & 1u)) & 0xffff0000u;
    return ua | ub;
}

// ---------------- pass 1: fp32 -> bf16 precast of A and W ------------------
// A_bf16[8192][1536] = [spikes | z], W_bf16[1024][1536] = [Wi | Wr].
// MLP x4 (4 float4 tasks/thread, stride 256) — ~18 us measured (R5/R6).
__global__ __launch_bounds__(256) void precast_aw(
    const float* __restrict__ spikes, const float* __restrict__ zin,
    const float* __restrict__ Wi,     const float* __restrict__ Wr,
    unsigned short* __restrict__ Abf, unsigned short* __restrict__ Wbf)
{
    const int base = blockIdx.x * 1024 + threadIdx.x;
    const float4* src[4];
    #pragma unroll
    for (int k = 0; k < 4; ++k) {
        const int idx = base + k * 256;
        if (idx < A4_COUNT) {
            const int row = idx / 384, c4 = idx - row * 384;
            src[k] = (const float4*)((c4 < 128)
                         ? spikes + (size_t)row * IN_F + c4 * 4
                         : zin    + (size_t)row * OUT_F + (c4 - 128) * 4);
        } else {
            const int w = idx - A4_COUNT;
            const int row = w / 384, c4 = w - row * 384;
            src[k] = (const float4*)((c4 < 128)
                         ? Wi + (size_t)row * IN_F + c4 * 4
                         : Wr + (size_t)row * OUT_F + (c4 - 128) * 4);
        }
    }
    float4 val[4];
    #pragma unroll
    for (int k = 0; k < 4; ++k) val[k] = *src[k];
    #pragma unroll
    for (int k = 0; k < 4; ++k) {
        const int idx = base + k * 256;
        unsigned short* dst = (idx < A4_COUNT)
                                  ? Abf + (size_t)idx * 4
                                  : Wbf + (size_t)(idx - A4_COUNT) * 4;
        uint2 pk = { pack2bf(val[k].x, val[k].y), pack2bf(val[k].z, val[k].w) };
        *(uint2*)dst = pk;
    }
}

// ---------------- pass 2: GEMM + in-block fused pointwise ------------------
// R6 post-mortem: MfmaUtil 9.7 / 40% occupancy / 3.2 TB/s — latency-bound at
// the per-iter vmcnt(0)+barrier with only ~3 resident blocks/CU to hide it.
// Fix: BK=32 halves LDS to 16 KB and staging to 2 gload_lds/thread/iter;
// __launch_bounds__(256,8) -> 8 blocks/CU (100% occupancy target). Latency
// is now covered by TLP (8 co-resident blocks) instead of per-block overlap.
// Swizzle re-derived for 4-chunk rows: slot = c ^ ((r>>1)&3); read fragment
// lanes hit quad-bank starts {0,16,4,20,8,24,12,28} -> 2-way aliasing (free).
// Pointwise planes (z,v,b) are fused per-block over the block's OWN 64x64
// tile, so the epilogue's i re-read is L1/L2-warm.
__global__ __launch_bounds__(256, 8) void lsnn_gemm(
    const unsigned short* __restrict__ Abf,   // [8192, 1536] bf16
    const unsigned short* __restrict__ Wbf,   // [1024, 1536] bf16
    const float* __restrict__ vin,
    const float* __restrict__ iin,
    const float* __restrict__ bin,
    float* __restrict__ out)                  // all 4 planes
{
    __shared__ unsigned short As[2][BM * BK];   // 2 x 4 KB
    __shared__ unsigned short Ws[2][BN * BK];   // 2 x 4 KB

    const int tid = threadIdx.x;
    const int bid = blockIdx.x;                 // 0..2047
    // bid&15 -> n-tile: XCD = bid%8 sees n-tiles {j, j+8} only -> 2 W slices
    // (2 x 192 KB) pinned per XCD L2 for the whole dispatch.
    const int n0 = (bid & 15) * BN;
    const int m0 = (bid >> 4) * BM;

    // ---- pointwise prefetch over this block's own 64x64 tile ----
    // 1024 f4 in the tile; thread gets 4 (j = k*256+tid): row j>>4, f4col j&15.
    // 16-lane row segments = 256B coalesced chunks.
    const f4* v4 = (const f4*)vin;
    const f4* i4 = (const f4*)iin;
    const f4* b4 = (const f4*)bin;
    size_t pidx[4];
    #pragma unroll
    for (int k = 0; k < 4; ++k) {
        const int j = k * 256 + tid;
        pidx[k] = (size_t)(m0 + (j >> 4)) * (OUT_F / 4) + (n0 >> 2) + (j & 15);
    }
    f4 vv[4], ii[4], bb[4];
    #pragma unroll
    for (int k = 0; k < 4; ++k) vv[k] = v4[pidx[k]];
    #pragma unroll
    for (int k = 0; k < 4; ++k) ii[k] = i4[pidx[k]];
    #pragma unroll
    for (int k = 0; k < 4; ++k) bb[k] = b4[pidx[k]];

    // ---- gemm geometry ----
    const int lane = tid & 63;
    const int wave = tid >> 6;
    const int wm = (wave >> 1) * 32;   // 2x2 wave grid over 64x64
    const int wn = (wave & 1) * 32;
    const int lr = lane & 15;
    const int lq = lane >> 4;

    f4 acc[2][2];
    #pragma unroll
    for (int a = 0; a < 2; ++a)
        #pragma unroll
        for (int b = 0; b < 2; ++b)
            acc[a][b] = (f4)0.0f;

    const unsigned short* Ab = Abf + (size_t)m0 * K_TOT;
    const unsigned short* Wb = Wbf + (size_t)n0 * K_TOT;

    // Staging geometry: 256 chunks (64 rows x 4), 1 chunk/thread for A and W.
    // LDS dest is linear (wave-uniform base + lane*16, gload_lds rule); the
    // swizzle lives in the SOURCE chunk column.
    const int rS = tid >> 2;                       // row 0..63
    const int cS = (tid & 3) ^ ((rS >> 1) & 3);    // swizzled source chunk
    const unsigned short* Asrc = Ab + (size_t)rS * K_TOT + cS * 8;
    const unsigned short* Wsrc = Wb + (size_t)rS * K_TOT + cS * 8;

    auto stage = [&](int buf, int kt) {
        __builtin_amdgcn_global_load_lds(
            (const __attribute__((address_space(1))) void*)(Asrc + kt),
            (__attribute__((address_space(3))) void*)(&As[buf][tid * 8]),
            16, 0, 0);
        __builtin_amdgcn_global_load_lds(
            (const __attribute__((address_space(1))) void*)(Wsrc + kt),
            (__attribute__((address_space(3))) void*)(&Ws[buf][tid * 8]),
            16, 0, 0);
    };

    stage(0, 0);
    __syncthreads();

    int cur = 0;
    for (int it = 0; it < NITER; ++it) {
        if (it + 1 < NITER) stage(cur ^ 1, (it + 1) * BK);

        // single K-step (BK=32 = one mfma_16x16x32): chunk col = lq
        bfrag af[2], wf[2];
        #pragma unroll
        for (int t = 0; t < 2; ++t) {
            const int row = wm + t * 16 + lr;
            af[t] = *(const bfrag*)&As[cur][row * BK + ((lq ^ ((row >> 1) & 3)) << 3)];
        }
        #pragma unroll
        for (int t = 0; t < 2; ++t) {
            const int row = wn + t * 16 + lr;
            wf[t] = *(const bfrag*)&Ws[cur][row * BK + ((lq ^ ((row >> 1) & 3)) << 3)];
        }
        #pragma unroll
        for (int tm = 0; tm < 2; ++tm)
            #pragma unroll
            for (int tn = 0; tn < 2; ++tn)
                acc[tm][tn] = __builtin_amdgcn_mfma_f32_16x16x32_bf16(
                    af[tm], wf[tn], acc[tm][tn], 0, 0, 0);

        __syncthreads();   // vmcnt(0)+barrier: drains tile t+1, after compute
        cur ^= 1;
    }

    // ---- write-late pointwise planes (z, v, b) from prefetched regs ----
    const size_t PL = (size_t)B_ROWS * OUT_F;
    #pragma unroll
    for (int k = 0; k < 4; ++k) {
        f4 z, vn, bn;
        #pragma unroll
        for (int c = 0; c < 4; ++c) {
            const float v_dec = vv[k][c] + 0.1f * (ii[k][c] - vv[k][c]);
            const float b_dec = bb[k][c] + 1.25e-06f * (1.0f - bb[k][c]);
            const float zz = (v_dec - b_dec > 0.0f) ? 1.0f : 0.0f;
            z[c]  = zz;
            vn[c] = (1.0f - zz) * v_dec;
            bn[c] = b_dec + zz * 0.00225f;
        }
        __builtin_nontemporal_store(z,  (f4*)out + pidx[k]);             // plane 0
        __builtin_nontemporal_store(vn, (f4*)(out + PL) + pidx[k]);      // plane 1
        __builtin_nontemporal_store(bn, (f4*)(out + 3 * PL) + pidx[k]);  // plane 3
    }

    // ---- epilogue: GEMM-dependent plane (i_new = i_decayed + acc) ----
    // i re-read is L1/L2-warm (this block just loaded its own tile of i).
    // C/D mapping col = lane&15, row = (lane>>4)*4 + reg (m89/m91).
    const size_t PL2 = 2 * PL;
    #pragma unroll
    for (int tm = 0; tm < 2; ++tm) {
        #pragma unroll
        for (int tn = 0; tn < 2; ++tn) {
            #pragma unroll
            for (int r = 0; r < 4; ++r) {
                const int gm = m0 + wm + tm * 16 + lq * 4 + r;
                const int gn = n0 + wn + tn * 16 + lr;
                const size_t idx = (size_t)gm * OUT_F + gn;
                const float i = iin[idx];
                __builtin_nontemporal_store((i - 0.2f * i) + acc[tm][tn][r],
                                            &out[PL2 + idx]);
            }
        }
    }
}

extern "C" void kernel_launch(void* const* d_in, const int* in_sizes, int n_in,
                              void* d_out, int out_size, void* d_ws, size_t ws_size,
                              hipStream_t stream) {
    const float* spikes = (const float*)d_in[0];
    const float* z      = (const float*)d_in[1];
    const float* v      = (const float*)d_in[2];
    const float* i      = (const float*)d_in[3];
    const float* b      = (const float*)d_in[4];
    const float* Wi     = (const float*)d_in[5];
    const float* Wr     = (const float*)d_in[6];
    float* out = (float*)d_out;

    unsigned short* Abf = (unsigned short*)d_ws;                       // 25,165,824 B
    unsigned short* Wbf = Abf + (size_t)B_ROWS * K_TOT;                //  3,145,728 B

    precast_aw<<<CAST_BLOCKS, 256, 0, stream>>>(spikes, z, Wi, Wr, Abf, Wbf);

    lsnn_gemm<<<GEMM_BLOCKS, 256, 0, stream>>>(Abf, Wbf, v, i, b, out);
}

// Round 9
// 299.515 us; speedup vs baseline: 1.1662x; 1.1662x over previous
//
#include <hip/hip_runtime.h>

#define B_ROWS 8192
#define IN_F 512
#define OUT_F 1024
#define K_TOT 1536

#define BM 64
#define BN 64
#define BK 64
#define NITER (K_TOT / BK)          // 24

#define A4_COUNT (B_ROWS * (K_TOT / 4))       // 3,145,728 float4 tasks
#define W4_COUNT (OUT_F  * (K_TOT / 4))       //   393,216
#define CAST_BLOCKS ((A4_COUNT + W4_COUNT) / 1024)   // 3456 (4 tasks/thread)
#define GEMM_BLOCKS ((B_ROWS / BM) * (OUT_F / BN))   // 2048

typedef short bfrag __attribute__((ext_vector_type(8)));   // 8 bf16 = 4 VGPRs
typedef float f4    __attribute__((ext_vector_type(4)));

// round-to-nearest-even fp32 -> bf16, packed pairwise into a dword
__device__ __forceinline__ unsigned int pack2bf(float a, float b) {
    unsigned int ua = __float_as_uint(a);
    unsigned int ub = __float_as_uint(b);
    ua = (ua + 0x7fffu + ((ua >> 16) & 1u)) >> 16;
    ub = (ub + 0x7fffu + ((ub >> 16) & 1u)) & 0xffff0000u;
    return ua | ub;
}

// ---------------- pass 1: fp32 -> bf16 precast of A and W ------------------
// A_bf16[8192][1536] = [spikes | z], W_bf16[1024][1536] = [Wi | Wr].
// MLP x4 (4 float4 tasks/thread, stride 256) — ~18 us measured (R5/R6).
__global__ __launch_bounds__(256) void precast_aw(
    const float* __restrict__ spikes, const float* __restrict__ zin,
    const float* __restrict__ Wi,     const float* __restrict__ Wr,
    unsigned short* __restrict__ Abf, unsigned short* __restrict__ Wbf)
{
    const int base = blockIdx.x * 1024 + threadIdx.x;
    const float4* src[4];
    #pragma unroll
    for (int k = 0; k < 4; ++k) {
        const int idx = base + k * 256;
        if (idx < A4_COUNT) {
            const int row = idx / 384, c4 = idx - row * 384;
            src[k] = (const float4*)((c4 < 128)
                         ? spikes + (size_t)row * IN_F + c4 * 4
                         : zin    + (size_t)row * OUT_F + (c4 - 128) * 4);
        } else {
            const int w = idx - A4_COUNT;
            const int row = w / 384, c4 = w - row * 384;
            src[k] = (const float4*)((c4 < 128)
                         ? Wi + (size_t)row * IN_F + c4 * 4
                         : Wr + (size_t)row * OUT_F + (c4 - 128) * 4);
        }
    }
    float4 val[4];
    #pragma unroll
    for (int k = 0; k < 4; ++k) val[k] = *src[k];
    #pragma unroll
    for (int k = 0; k < 4; ++k) {
        const int idx = base + k * 256;
        unsigned short* dst = (idx < A4_COUNT)
                                  ? Abf + (size_t)idx * 4
                                  : Wbf + (size_t)(idx - A4_COUNT) * 4;
        uint2 pk = { pack2bf(val[k].x, val[k].y), pack2bf(val[k].z, val[k].w) };
        *(uint2*)dst = pk;
    }
}

// ---------------- pass 2: GEMM + in-block fused pointwise ------------------
// R6 structure (best measured: 101 us) upgraded with a 3-deep LDS pipeline +
// COUNTED vmcnt (T4). R8 lesson: the per-iter vmcnt(0) convoy is the
// bottleneck, not TLP. Buffers cycle t%3; per iter:
//   stage((t+2)%3)  ->  compute buf[t%3]  ->  s_waitcnt vmcnt(4)  ->  s_barrier
// vmcnt(4) retires exactly tile (t+1)'s 4 gload_lds (oldest outstanding),
// leaving tile (t+2)'s 4 in flight across the barrier — each tile's loads
// get a full iteration of compute + a barrier to land. WAR safe: a buffer is
// overwritten two iters after its last ds_read, past a barrier. No
// sched_barrier pins (m141/R2 lesson); lgkm deps compiler-managed.
// Tail: stage wraps to kt=0 into the dead buffer (uniform vmcnt arithmetic).
__global__ __launch_bounds__(256, 3) void lsnn_gemm(
    const unsigned short* __restrict__ Abf,   // [8192, 1536] bf16
    const unsigned short* __restrict__ Wbf,   // [1024, 1536] bf16
    const float* __restrict__ vin,
    const float* __restrict__ iin,
    const float* __restrict__ bin,
    float* __restrict__ out)                  // all 4 planes
{
    __shared__ unsigned short As[3][BM * BK];   // 3 x 8 KB
    __shared__ unsigned short Ws[3][BN * BK];   // 3 x 8 KB  (48 KB total)

    const int tid = threadIdx.x;
    const int bid = blockIdx.x;                 // 0..2047
    // bid&15 -> n-tile: XCD = bid%8 sees n-tiles {j, j+8} only -> 2 W slices
    // (2 x 192 KB) pinned per XCD L2 for the whole dispatch.
    const int n0 = (bid & 15) * BN;
    const int m0 = (bid >> 4) * BM;

    // ---- fused pointwise slice (R6's proven linear mapping) ----
    // 12 f4 loads; compiler sinks them toward the epilogue (R6: VGPR 52) —
    // fine, they are outside the K-loop either way so the in-loop vmcnt
    // arithmetic counts only our gload_lds.
    const int pw = bid * 1024 + tid;            // f4 index into [B, OUT_F]
    const f4* v4 = (const f4*)vin;
    const f4* i4 = (const f4*)iin;
    const f4* b4 = (const f4*)bin;
    f4 vv[4], ii[4], bb[4];
    #pragma unroll
    for (int k = 0; k < 4; ++k) vv[k] = v4[pw + k * 256];
    #pragma unroll
    for (int k = 0; k < 4; ++k) ii[k] = i4[pw + k * 256];
    #pragma unroll
    for (int k = 0; k < 4; ++k) bb[k] = b4[pw + k * 256];

    // ---- gemm geometry ----
    const int lane = tid & 63;
    const int wave = tid >> 6;
    const int wm = (wave >> 1) * 32;   // 2x2 wave grid over 64x64
    const int wn = (wave & 1) * 32;
    const int lr = lane & 15;
    const int lq = lane >> 4;

    f4 acc[2][2];
    #pragma unroll
    for (int a = 0; a < 2; ++a)
        #pragma unroll
        for (int b = 0; b < 2; ++b)
            acc[a][b] = (f4)0.0f;

    const unsigned short* Ab = Abf + (size_t)m0 * K_TOT;
    const unsigned short* Wb = Wbf + (size_t)n0 * K_TOT;

    // Staging geometry: 512 chunks/tile (64 rows x 8), XOR swizzle
    // slot = c ^ (r&7) (verified 0-conflict). 8 rows x 8 lanes per inst
    // -> 8x128B coalesced global segments.
    int rr[2], cc_[2], jj[2];
    #pragma unroll
    for (int p = 0; p < 2; ++p) {
        const int q = p * 256 + wave * 64 + lane;   // chunk 0..511
        rr[p] = q >> 3;
        cc_[p] = (q & 7) ^ (rr[p] & 7);
        jj[p] = p * 256 + wave * 64;
    }

    auto stage = [&](int buf, int kt) {
        #pragma unroll
        for (int p = 0; p < 2; ++p)
            __builtin_amdgcn_global_load_lds(
                (const __attribute__((address_space(1))) void*)(Ab + (size_t)rr[p] * K_TOT + kt + cc_[p] * 8),
                (__attribute__((address_space(3))) void*)(&As[buf][jj[p] * 8]),
                16, 0, 0);
        #pragma unroll
        for (int p = 0; p < 2; ++p)
            __builtin_amdgcn_global_load_lds(
                (const __attribute__((address_space(1))) void*)(Wb + (size_t)rr[p] * K_TOT + kt + cc_[p] * 8),
                (__attribute__((address_space(3))) void*)(&Ws[buf][jj[p] * 8]),
                16, 0, 0);
    };

    // prologue: tiles 0 and 1 in flight; wait for tile 0 only (vmcnt(4)).
    stage(0, 0);
    stage(1, BK);
    asm volatile("s_waitcnt vmcnt(4)" ::: "memory");
    __builtin_amdgcn_s_barrier();

    for (int it = 0; it < NITER; ++it) {
        // stage tile t+2 (wrap to kt=0 into the dead buffer at the tail)
        const int t2 = it + 2;
        stage(t2 % 3, (t2 < NITER) ? t2 * BK : 0);

        // compute on buf[t%3] (resident since prior iteration's wait)
        const unsigned short* Ac = As[it % 3];
        const unsigned short* Wc = Ws[it % 3];
        #pragma unroll
        for (int ks = 0; ks < 2; ++ks) {
            const int cc = ks * 4 + lq;
            bfrag af[2], wf[2];
            #pragma unroll
            for (int t = 0; t < 2; ++t) {
                const int row = wm + t * 16 + lr;
                af[t] = *(const bfrag*)&Ac[row * BK + ((cc ^ (row & 7)) << 3)];
            }
            #pragma unroll
            for (int t = 0; t < 2; ++t) {
                const int row = wn + t * 16 + lr;
                wf[t] = *(const bfrag*)&Wc[row * BK + ((cc ^ (row & 7)) << 3)];
            }
            #pragma unroll
            for (int tm = 0; tm < 2; ++tm)
                #pragma unroll
                for (int tn = 0; tn < 2; ++tn)
                    acc[tm][tn] = __builtin_amdgcn_mfma_f32_16x16x32_bf16(
                        af[tm], wf[tn], acc[tm][tn], 0, 0, 0);
        }

        // counted drain: retire tile (t+1)'s 4 loads, keep (t+2)'s in flight
        asm volatile("s_waitcnt vmcnt(4)" ::: "memory");
        __builtin_amdgcn_s_barrier();
    }

    // ---- write-late pointwise planes (z, v, b) from prefetched regs ----
    const size_t PL = (size_t)B_ROWS * OUT_F;
    #pragma unroll
    for (int k = 0; k < 4; ++k) {
        f4 z, vn, bn;
        #pragma unroll
        for (int c = 0; c < 4; ++c) {
            const float v_dec = vv[k][c] + 0.1f * (ii[k][c] - vv[k][c]);
            const float b_dec = bb[k][c] + 1.25e-06f * (1.0f - bb[k][c]);
            const float zz = (v_dec - b_dec > 0.0f) ? 1.0f : 0.0f;
            z[c]  = zz;
            vn[c] = (1.0f - zz) * v_dec;
            bn[c] = b_dec + zz * 0.00225f;
        }
        const int j = pw + k * 256;
        __builtin_nontemporal_store(z,  (f4*)out + j);               // plane 0
        __builtin_nontemporal_store(vn, (f4*)(out + PL) + j);        // plane 1
        __builtin_nontemporal_store(bn, (f4*)(out + 3 * PL) + j);    // plane 3
    }

    // ---- epilogue: GEMM-dependent plane (i_new = i_decayed + acc) ----
    // C/D mapping col = lane&15, row = (lane>>4)*4 + reg (m89/m91).
    const size_t PL2 = 2 * PL;
    #pragma unroll
    for (int tm = 0; tm < 2; ++tm) {
        #pragma unroll
        for (int tn = 0; tn < 2; ++tn) {
            #pragma unroll
            for (int r = 0; r < 4; ++r) {
                const int gm = m0 + wm + tm * 16 + lq * 4 + r;
                const int gn = n0 + wn + tn * 16 + lr;
                const size_t idx = (size_t)gm * OUT_F + gn;
                const float i = iin[idx];
                __builtin_nontemporal_store((i - 0.2f * i) + acc[tm][tn][r],
                                            &out[PL2 + idx]);
            }
        }
    }
}

extern "C" void kernel_launch(void* const* d_in, const int* in_sizes, int n_in,
                              void* d_out, int out_size, void* d_ws, size_t ws_size,
                              hipStream_t stream) {
    const float* spikes = (const float*)d_in[0];
    const float* z      = (const float*)d_in[1];
    const float* v      = (const float*)d_in[2];
    const float* i      = (const float*)d_in[3];
    const float* b      = (const float*)d_in[4];
    const float* Wi     = (const float*)d_in[5];
    const float* Wr     = (const float*)d_in[6];
    float* out = (float*)d_out;

    unsigned short* Abf = (unsigned short*)d_ws;                       // 25,165,824 B
    unsigned short* Wbf = Abf + (size_t)B_ROWS * K_TOT;                //  3,145,728 B

    precast_aw<<<CAST_BLOCKS, 256, 0, stream>>>(spikes, z, Wi, Wr, Abf, Wbf);

    lsnn_gemm<<<GEMM_BLOCKS, 256, 0, stream>>>(Abf, Wbf, v, i, b, out);
}